// Round 9
// baseline (20.919 us; speedup 1.0000x reference)
//
#include <hip/hip_runtime.h>
#include <stdint.h>

// ACOLayer: reproduce JAX's sampling exactly.
//   u = jax.random.uniform(key(42), (32, 4096, 16), f32)
//   idx[b,i,a] = searchsorted(cdf_row_i, u[b,i,a]) clamped; -1 where a >= x[b,i]
// RNG: jax_threefry_partitionable=True stream:
//   bits[i] = o0 ^ o1, (o0,o1) = threefry2x32(key=(0,42), counter=(0, i))
//   u = bitcast((bits>>9)|0x3f800000) - 1.0f
// Search: unnormalized cumsum, target u*total.
//
// Round 9 = round 8 (best, 20.91us) + critical-path shortening, same structure:
//  (1) threefry moved BEFORE the scan -> its ~140 VALU instrs execute in the
//      global-load-wait shadow instead of serializing after barrier 2.
//  (2) first 4 search levels via a register tree over the 15 dyadic nodes
//      cdf[k*256] (one parallel broadcast-read stage + cndmask tree), then the
//      two draws' remaining 8-step searches run FUSED (2 independent probes
//      per stage). Dependent-LDS chain: 12 stages -> 1 + 8.

#define N_IN    4096
#define N_OUT   4096
#define BS      32
#define MAX_A   16
#define THREADS 256
#define HALF    1048576u  /* 16 * N_IN * MAX_A */

// +1 word per 32: spreads power-of-2 probe strides across banks
__device__ __forceinline__ int padi(int j) { return j + (j >> 5); }

__device__ __forceinline__ uint32_t rotl32(uint32_t x, uint32_t r) {
    return (x << r) | (x >> (32u - r));
}

// Threefry-2x32, 20 rounds, key (0, 42) — jax.random.key(42)
__device__ __forceinline__ void threefry2x32_42(uint32_t x0, uint32_t x1,
                                                uint32_t& o0, uint32_t& o1) {
    const uint32_t k0 = 0u, k1 = 42u;
    const uint32_t k2 = k0 ^ k1 ^ 0x1BD11BDAu;
    x0 += k0; x1 += k1;
#define TF_R(r) { x0 += x1; x1 = rotl32(x1, (r)); x1 ^= x0; }
    TF_R(13) TF_R(15) TF_R(26) TF_R(6)
    x0 += k1; x1 += k2 + 1u;
    TF_R(17) TF_R(29) TF_R(16) TF_R(24)
    x0 += k2; x1 += k0 + 2u;
    TF_R(13) TF_R(15) TF_R(26) TF_R(6)
    x0 += k0; x1 += k1 + 3u;
    TF_R(17) TF_R(29) TF_R(16) TF_R(24)
    x0 += k1; x1 += k2 + 4u;
    TF_R(13) TF_R(15) TF_R(26) TF_R(6)
    x0 += k2; x1 += k0 + 5u;
#undef TF_R
    o0 = x0; o1 = x1;
}

__device__ __forceinline__ float bits_to_uniform(uint32_t b) {
    uint32_t f = (b >> 9) | 0x3f800000u;
    float r;
    __builtin_memcpy(&r, &f, 4);
    return r - 1.0f;
}

// First 4 lower_bound levels as a pure-register cndmask tree over the 15
// dyadic nodes Tk = cdf[k*256] (heap order: depth1 T8; depth2 T4,T12; ...).
// Probe positions are identical to the LDS loop's first 4 iterations.
// Returns j in [0,16): the answer lies in [j*256, (j+1)*256] (+-1 slack).
__device__ __forceinline__ int tree4(float t,
    float T1, float T2, float T3, float T4, float T5, float T6, float T7,
    float T8, float T9, float T10, float T11, float T12, float T13,
    float T14, float T15) {
    const bool c1 = (T8 < t);
    const float m2 = c1 ? T12 : T4;
    const bool c2 = (m2 < t);
    const float ma = c2 ? T6  : T2;
    const float mb = c2 ? T14 : T10;
    const float m3 = c1 ? mb : ma;
    const bool c3 = (m3 < t);
    const float a1 = c3 ? T3  : T1;
    const float a2 = c3 ? T7  : T5;
    const float a3 = c3 ? T11 : T9;
    const float a4 = c3 ? T15 : T13;
    const float b1 = c2 ? a2 : a1;
    const float b2 = c2 ? a4 : a3;
    const float m4 = c1 ? b2 : b1;
    const bool c4 = (m4 < t);
    return (c1 ? 8 : 0) | (c2 ? 4 : 0) | (c3 ? 2 : 0) | (c4 ? 1 : 0);
}

__global__ __launch_bounds__(THREADS)
void aco_sample_kernel(const int* __restrict__ x,
                       const float* __restrict__ w,
                       int* __restrict__ out) {
    __shared__ float cdf[N_OUT + (N_OUT >> 5)];  // +1/32 padded
    __shared__ float wsum[4];
    __shared__ int   xc[BS];

    const int row  = blockIdx.x;
    const int t    = threadIdx.x;
    const int lane = t & 63;
    const int wid  = t >> 6;

    // ---- stage 16 weights directly into registers (4x float4) ----
    const float4* wrow = (const float4*)(w + (size_t)row * N_OUT);
    float4 v0 = wrow[t * 4 + 0];
    float4 v1 = wrow[t * 4 + 1];
    float4 v2 = wrow[t * 4 + 2];
    float4 v3 = wrow[t * 4 + 3];

    if (t < BS) xc[t] = x[t * N_IN + row];

    // ---- threefry in the global-load-wait shadow (no memory deps) ----
    const int bb = t >> 4;
    const int aa = t & 15;
    const uint32_t j0 = (uint32_t)(bb * (N_IN * MAX_A) + row * MAX_A + aa);
    const uint32_t j1 = j0 + HALF;
    uint32_t o0, o1, p0, p1;
    threefry2x32_42(0u, j0, o0, o1);
    threefry2x32_42(0u, j1, p0, p1);
    const float u0 = bits_to_uniform(o0 ^ o1);
    const float u1 = bits_to_uniform(p0 ^ p1);

    // ---- local inclusive scan of 16 values in registers ----
    float loc[16];
    {
        float s = 0.f;
        s += v0.x; loc[0]  = s;  s += v0.y; loc[1]  = s;
        s += v0.z; loc[2]  = s;  s += v0.w; loc[3]  = s;
        s += v1.x; loc[4]  = s;  s += v1.y; loc[5]  = s;
        s += v1.z; loc[6]  = s;  s += v1.w; loc[7]  = s;
        s += v2.x; loc[8]  = s;  s += v2.y; loc[9]  = s;
        s += v2.z; loc[10] = s;  s += v2.w; loc[11] = s;
        s += v3.x; loc[12] = s;  s += v3.y; loc[13] = s;
        s += v3.z; loc[14] = s;  s += v3.w; loc[15] = s;
    }
    const float my_total = loc[15];

    // ---- wave-level inclusive scan of per-thread totals ----
    float incl = my_total;
    #pragma unroll
    for (int d = 1; d < 64; d <<= 1) {
        float n = __shfl_up(incl, d, 64);
        if (lane >= d) incl += n;
    }
    if (lane == 63) wsum[wid] = incl;
    __syncthreads();   // B1: wsum visible

    const float4 ws = *(const float4*)wsum;
    const float total = ws.x + ws.y + ws.z + ws.w;
    float wprefix = 0.f;
    if (wid > 0) wprefix += ws.x;
    if (wid > 1) wprefix += ws.y;
    if (wid > 2) wprefix += ws.z;
    const float chunk_prefix = wprefix + incl - my_total;

    // ---- write unnormalized cumsum to LDS (16 scalar writes, banks spread) ----
    {
        const int base = t * 16;
        #pragma unroll
        for (int m = 0; m < 16; ++m)
            cdf[padi(base + m)] = chunk_prefix + loc[m];
    }
    __syncthreads();   // B2: full cdf visible

    // ---- preload 15 dyadic tree nodes (broadcast reads, one latency stage) ----
    const float T1  = cdf[padi( 1 << 8)];
    const float T2  = cdf[padi( 2 << 8)];
    const float T3  = cdf[padi( 3 << 8)];
    const float T4  = cdf[padi( 4 << 8)];
    const float T5  = cdf[padi( 5 << 8)];
    const float T6  = cdf[padi( 6 << 8)];
    const float T7  = cdf[padi( 7 << 8)];
    const float T8  = cdf[padi( 8 << 8)];
    const float T9  = cdf[padi( 9 << 8)];
    const float T10 = cdf[padi(10 << 8)];
    const float T11 = cdf[padi(11 << 8)];
    const float T12 = cdf[padi(12 << 8)];
    const float T13 = cdf[padi(13 << 8)];
    const float T14 = cdf[padi(14 << 8)];
    const float T15 = cdf[padi(15 << 8)];

    const float t0 = u0 * total;
    const float t1 = u1 * total;

    // ---- levels 1-4 in registers, then fused 8-step dual search ----
    const int ja = tree4(t0, T1,T2,T3,T4,T5,T6,T7,T8,T9,T10,T11,T12,T13,T14,T15);
    const int jb = tree4(t1, T1,T2,T3,T4,T5,T6,T7,T8,T9,T10,T11,T12,T13,T14,T15);
    int lo0 = ja << 8, hi0 = lo0 + 256;
    int lo1 = jb << 8, hi1 = lo1 + 256;
    #pragma unroll
    for (int it = 0; it < 8; ++it) {
        const int m0 = (lo0 + hi0) >> 1;
        const int m1 = (lo1 + hi1) >> 1;
        const float f0 = cdf[padi(m0)];   // independent probes: MLP = 2
        const float f1 = cdf[padi(m1)];
        if (f0 < t0) lo0 = m0 + 1; else hi0 = m0;
        if (f1 < t1) lo1 = m1 + 1; else hi1 = m1;
    }
    const int idx0 = lo0 < N_OUT ? lo0 : N_OUT - 1;
    const int idx1 = lo1 < N_OUT ? lo1 : N_OUT - 1;

    out[j0] = (aa < xc[bb])      ? idx0 : -1;
    out[j1] = (aa < xc[bb + 16]) ? idx1 : -1;
}

extern "C" void kernel_launch(void* const* d_in, const int* in_sizes, int n_in,
                              void* d_out, int out_size, void* d_ws, size_t ws_size,
                              hipStream_t stream) {
    // select inputs by size (robust to ordering):
    //   x: 32*4096 int32; weights: 4096*4096 f32
    const int*   x;
    const float* w;
    if (in_sizes[0] == BS * N_IN) { x = (const int*)d_in[0]; w = (const float*)d_in[1]; }
    else                          { x = (const int*)d_in[1]; w = (const float*)d_in[0]; }
    aco_sample_kernel<<<N_IN, THREADS, 0, stream>>>(x, w, (int*)d_out);
}